// Round 9
// baseline (999.510 us; speedup 1.0000x reference)
//
#include <hip/hip_runtime.h>
#include <stdint.h>
#include <stddef.h>

#define NB   16
#define CIN  512
#define COUT 512
#define KK   1024

#define MARGIN    2e-5f
#define INV_SCALE 0.04419417382415922f   // 1/sqrt(512)

typedef short short4v __attribute__((ext_vector_type(4)));
typedef short short8v __attribute__((ext_vector_type(8)));
typedef float f32x4  __attribute__((ext_vector_type(4)));

union Frag { short4v h[2]; short8v v8; };

// ---------------- threefry2x32 (JAX-compatible, 20 rounds) ----------------
__host__ __device__ inline void tf2x32(uint32_t k0, uint32_t k1,
                                       uint32_t x0, uint32_t x1,
                                       uint32_t& o0, uint32_t& o1) {
  uint32_t ks2 = k0 ^ k1 ^ 0x1BD11BDAu;
  x0 += k0; x1 += k1;
#define TF_RND(r) { x0 += x1; x1 = (x1 << r) | (x1 >> (32 - r)); x1 ^= x0; }
  TF_RND(13) TF_RND(15) TF_RND(26) TF_RND(6)
  x0 += k1;  x1 += ks2 + 1u;
  TF_RND(17) TF_RND(29) TF_RND(16) TF_RND(24)
  x0 += ks2; x1 += k0 + 2u;
  TF_RND(13) TF_RND(15) TF_RND(26) TF_RND(6)
  x0 += k0;  x1 += k1 + 3u;
  TF_RND(17) TF_RND(29) TF_RND(16) TF_RND(24)
  x0 += k1;  x1 += ks2 + 4u;
  TF_RND(13) TF_RND(15) TF_RND(26) TF_RND(6)
  x0 += ks2; x1 += k0 + 5u;
#undef TF_RND
  o0 = x0; o1 = x1;
}

__device__ inline float bits_to_u(uint32_t b) {
  return __uint_as_float((b >> 9) | 0x3f800000u) - 1.0f;
}

__device__ __host__ inline uint16_t f2bf(float f) {
  union { float f; uint32_t u; } c; c.f = f;
  uint32_t r = (c.u + 0x7fffu + ((c.u >> 16) & 1u)) >> 16;
  return (uint16_t)r;
}
__device__ inline float bf2f(uint16_t h) {
  union { uint32_t u; float f; } c; c.u = ((uint32_t)h) << 16;
  return c.f;
}

// permuted column position inside a 32-c slice: group g holds {4g..4g+3, 4g+16..4g+19}
__device__ inline int permpos(int c) {
  const int base32 = c & ~31, within = c & 31;
  const int g = (within >> 2) & 3;
  const int e = (within & 16) ? (4 + (within & 3)) : (within & 3);
  return base32 + g * 8 + e;
}

// ---------------- kmatT64[o][k] (f64), v[k][o] = codebook @ wv^T (f32) ----------------
__global__ __launch_bounds__(256) void k_prep(const float* __restrict__ cb,
                                              const float* __restrict__ wk,
                                              const float* __restrict__ wv,
                                              double* __restrict__ kmatT64,
                                              float* __restrict__ v) {
  __shared__ __align__(16) float rows[8][CIN];
  const int k0 = blockIdx.x * 8;
  const int t = threadIdx.x;
#pragma unroll
  for (int kk = 0; kk < 8; ++kk)
    for (int c = t; c < CIN; c += 256) rows[kk][c] = cb[(size_t)(k0 + kk) * CIN + c];
  __syncthreads();
#pragma unroll
  for (int oo = 0; oo < 2; ++oo) {
    const int o = t + oo * 256;
    const float* kr = wk + (size_t)o * CIN;
    const float* vr = wv + (size_t)o * CIN;
    double ak[8] = {0,0,0,0,0,0,0,0}, av[8] = {0,0,0,0,0,0,0,0};
    for (int c = 0; c < CIN; c += 4) {
      const float4 k4 = *(const float4*)(kr + c);
      const float4 v4 = *(const float4*)(vr + c);
#pragma unroll
      for (int kk = 0; kk < 8; ++kk) {
        const float4 c4 = *(const float4*)&rows[kk][c];
        ak[kk] += (double)c4.x * (double)k4.x + (double)c4.y * (double)k4.y
                + (double)c4.z * (double)k4.z + (double)c4.w * (double)k4.w;
        av[kk] += (double)c4.x * (double)v4.x + (double)c4.y * (double)v4.y
                + (double)c4.z * (double)v4.z + (double)c4.w * (double)v4.w;
      }
    }
#pragma unroll
    for (int kk = 0; kk < 8; ++kk) {
      kmatT64[(size_t)o * KK + k0 + kk] = ak[kk];
      v[(size_t)(k0 + kk) * COUT + o]  = (float)av[kk];
    }
  }
}

// ---- W[c][k]=sum_o wq[o][c]*kmat[k][o]; emit WT64[k][c] f64 + frag-major bf16 hi/lo ----
__global__ __launch_bounds__(256) void k_wfold(const float* __restrict__ wq,
                                               const double* __restrict__ kmatT64,
                                               double* __restrict__ WT64,
                                               uint16_t* __restrict__ Wph,
                                               uint16_t* __restrict__ Wpl) {
  __shared__ __align__(16) float  As[16][64];    // [o][c]
  __shared__ __align__(16) double Bs[16][128];   // [o][k]
  const int t  = threadIdx.x;
  const int cb = (blockIdx.x >> 3) * 64;
  const int kb = (blockIdx.x & 7) * 128;
  const int tc = t >> 4, tk = t & 15;

  double acc[4][8];
#pragma unroll
  for (int i = 0; i < 4; ++i)
#pragma unroll
    for (int j = 0; j < 8; ++j) acc[i][j] = 0.0;

  for (int o0 = 0; o0 < COUT; o0 += 16) {
    {
      const int o2 = t >> 4, c4 = (t & 15) * 4;
      float4 f = *(const float4*)&wq[(size_t)(o0 + o2) * CIN + cb + c4];
      As[o2][c4+0] = f.x; As[o2][c4+1] = f.y; As[o2][c4+2] = f.z; As[o2][c4+3] = f.w;
    }
    {
      const int o2 = t >> 4, k8 = (t & 15) * 8;
      const double* src = &kmatT64[(size_t)(o0 + o2) * KK + kb + k8];
#pragma unroll
      for (int j = 0; j < 8; ++j) Bs[o2][k8 + j] = src[j];
    }
    __syncthreads();
#pragma unroll 4
    for (int o2 = 0; o2 < 16; ++o2) {
      double a[4], b[8];
#pragma unroll
      for (int i = 0; i < 4; ++i) a[i] = (double)As[o2][tc*4 + i];
#pragma unroll
      for (int j = 0; j < 8; ++j) b[j] = Bs[o2][tk*8 + j];
#pragma unroll
      for (int i = 0; i < 4; ++i)
#pragma unroll
        for (int j = 0; j < 8; ++j) acc[i][j] += a[i] * b[j];
    }
    __syncthreads();
  }
#pragma unroll
  for (int i = 0; i < 4; ++i) {
    const int c = cb + tc*4 + i;
    const int pp = permpos(c);
#pragma unroll
    for (int j = 0; j < 8; ++j) {
      const int k = kb + tk*8 + j;
      const double a = acc[i][j];
      WT64[(size_t)k * CIN + c] = a;
      const float wf = (float)a;
      const uint16_t hb = f2bf(wf);
      const float lof = wf - bf2f(hb);
      Wph[(size_t)k * CIN + pp] = hb;
      Wpl[(size_t)k * CIN + pp] = f2bf(lof);
    }
  }
}

// ---------------- latent NCHW f32 -> Apk[cs][p][8 quads of [hi4|lo4]] ----------------
__global__ __launch_bounds__(256) void k_aprep(const float* __restrict__ latent,
                                               uint16_t* __restrict__ Apk) {
  __shared__ float T[128][68];
  const int rb = blockIdx.x, n = rb >> 6, h = rb & 63, t = threadIdx.x;
  for (int c0 = 0; c0 < 512; c0 += 128) {
    const int c2 = t >> 1, wh = (t & 1) * 32;
    const float* src = latent + (size_t)n * 2097152 + (size_t)(c0 + c2) * 4096 + h * 64 + wh;
#pragma unroll
    for (int i = 0; i < 8; ++i)
      *(float4*)&T[c2][wh + i*4] = *(const float4*)(src + i*4);
    __syncthreads();
    const int w = t & 63, cp = t >> 6;
    const int cs = (c0 >> 5) + cp;          // 0..15
    const int p = rb * 64 + w;
    uint16_t* dst = Apk + ((size_t)cs * 65536 + p) * 64;
#pragma unroll
    for (int q = 0; q < 8; ++q) {
      short8v vv;
#pragma unroll
      for (int j = 0; j < 4; ++j) {
        const float f = T[cp*32 + (q & 3) * 4 + (q >> 2) * 16 + j][w];
        const uint16_t hb = f2bf(f);
        vv[j]     = (short)hb;
        vv[4 + j] = (short)f2bf(f - bf2f(hb));
      }
      *(short8v*)(dst + q * 8) = vv;
    }
    __syncthreads();
  }
}

// ---- stage one (kcp, cs) slice: B for both kc of the pair (2x32 KB) + A (16 KB) ----
// 10 global_load_lds per thread -> vmcnt(10) is the counted wait.
#define STAGE(buf_, st_) do {                                              \
  const int kcp_ = (st_) >> 4, cs_ = (st_) & 15;                           \
  _Pragma("unroll")                                                        \
  for (int i_ = 0; i_ < 8; ++i_) {                                         \
    const int j_ = i_ >> 2, ii_ = i_ & 3;                                  \
    const int half_ = ii_ >> 1;                                            \
    const int D_ = (ii_ & 1) * 8192 + t * 16;                              \
    const int kcol_ = D_ >> 6;                                             \
    const int bs_ = ((D_ >> 4) & 3) ^ ((kcol_ >> 1) & 3);                  \
    const uint16_t* gsrc_ = (half_ ? Wpl : Wph) +                          \
        ((size_t)((kcp_ * 2 + j_) * 256 + kcol_) * 512 + cs_ * 32 + bs_ * 8); \
    char* ldst_ = smem + (buf_) * 65536 + j_ * 32768 + half_ * 16384 + D_; \
    __builtin_amdgcn_global_load_lds(                                      \
        (const __attribute__((address_space(1))) uint32_t*)gsrc_,          \
        (__attribute__((address_space(3))) uint32_t*)ldst_, 16, 0, 0);     \
  }                                                                        \
  _Pragma("unroll")                                                        \
  for (int i_ = 0; i_ < 2; ++i_) {                                         \
    const int D_ = i_ * 8192 + t * 16;                                     \
    const int row_ = D_ >> 7;                                              \
    const int q_ = ((D_ >> 4) & 7) ^ (row_ & 7);                           \
    const uint16_t* gsrc_ = Apk +                                          \
        ((size_t)cs_ * 65536 + pbase + row_) * 64 + q_ * 8;                \
    char* ldst_ = smem + 131072 + (buf_) * 16384 + D_;                     \
    __builtin_amdgcn_global_load_lds(                                      \
        (const __attribute__((address_space(1))) uint32_t*)gsrc_,          \
        (__attribute__((address_space(3))) uint32_t*)ldst_, 16, 0, 0);     \
  } } while (0)

#define BARRIER() do { __builtin_amdgcn_sched_barrier(0);                  \
  __builtin_amdgcn_s_barrier(); __builtin_amdgcn_sched_barrier(0); } while (0)
#define WAITV10() do { __builtin_amdgcn_sched_barrier(0);                  \
  asm volatile("s_waitcnt vmcnt(10)" ::: "memory");                        \
  __builtin_amdgcn_sched_barrier(0); } while (0)

// ---------------- logit GEMM: kc-paired, counted-vmcnt pipeline, fused argmax ----------------
__global__ __launch_bounds__(512, 2) void k_logit(
    const uint16_t* __restrict__ Apk,
    const uint16_t* __restrict__ Wph, const uint16_t* __restrict__ Wpl,
    const float* __restrict__ latent, const double* __restrict__ WT64,
    float* __restrict__ out_logit, int* __restrict__ trueCode, int* __restrict__ binCnt) {
  __shared__ __align__(16) char smem[163840];   // B 2buf x 2kc x 32KB | A 2buf x 16KB
  // post-loop scratch overlays the A region (only touched after the final barrier):
  float* rowBv   = (float*)(smem + 131072);                     // 128 f32
  int*   rowBk   = (int*)  (smem + 131072 + 512);               // 128 i32
  int*   candCnt = (int*)  (smem + 131072 + 1024);              // 128 i32
  int  (*candK)[8] = (int(*)[8])(smem + 131072 + 1536);         // 128x8 i32

  const int t = threadIdx.x;
  const int wave = t >> 6, lane = t & 63;
  const int wr = wave >> 2, wc = wave & 3;       // wr 0..1 (64-row halves), wc 0..3 (64-kcol quarters)
  const int rb = blockIdx.x;
  const int n = rb >> 5;                          // 128 rows per block
  const int pbase = rb * 128;
  const int lg = lane >> 4, l15 = lane & 15;

  float bestv[4][4]; int bestk[4][4];
#pragma unroll
  for (int rt = 0; rt < 4; ++rt)
#pragma unroll
    for (int reg = 0; reg < 4; ++reg) { bestv[rt][reg] = -1.0e30f; bestk[rt][reg] = 0; }

  f32x4 acc[2][4][4];

  STAGE(0, 0);
  STAGE(1, 1);

  for (int st = 0; st < 32; ++st) {
    const int cur = st & 1, kcp = st >> 4, cs = st & 15;
    WAITV10();                    // stage st landed; st+1's 10 loads stay in flight
    BARRIER();
    if (cs == 0) {
#pragma unroll
      for (int j = 0; j < 2; ++j)
#pragma unroll
        for (int rt = 0; rt < 4; ++rt)
#pragma unroll
          for (int ct = 0; ct < 4; ++ct) acc[j][rt][ct] = (f32x4){0.f, 0.f, 0.f, 0.f};
    }

    // A fragments from LDS (shared across both kc of the pair)
    const uint16_t* Ab = (const uint16_t*)(smem + 131072 + cur * 16384);
    Frag ah[4], al[4];
#pragma unroll
    for (int rt = 0; rt < 4; ++rt) {
      const int row = wr * 64 + rt * 16 + l15;
      const uint16_t* ab = Ab + row * 64;
      const int s0 = (lg ^ (row & 7)) * 8;
      Frag f0, f1;
      f0.v8 = *(const short8v*)(ab + s0);
      f1.v8 = *(const short8v*)(ab + (s0 ^ 32));
      ah[rt].h[0] = f0.h[0]; ah[rt].h[1] = f1.h[0];
      al[rt].h[0] = f0.h[1]; al[rt].h[1] = f1.h[1];
    }

#pragma unroll
    for (int j = 0; j < 2; ++j) {
      const uint16_t* Bb = (const uint16_t*)(smem + cur * 65536 + j * 32768);
#pragma unroll
      for (int ct = 0; ct < 4; ++ct) {
        const int kcol = wc * 64 + ct * 16 + l15;
        const int sw = lg ^ ((kcol >> 1) & 3);
        Frag bh, bl;
        bh.v8 = *(const short8v*)(Bb + kcol * 32 + sw * 8);
        bl.v8 = *(const short8v*)(Bb + 8192 + kcol * 32 + sw * 8);
#pragma unroll
        for (int rt = 0; rt < 4; ++rt) {
          acc[j][rt][ct] = __builtin_amdgcn_mfma_f32_16x16x32_bf16(ah[rt].v8, bh.v8, acc[j][rt][ct], 0, 0, 0);
          acc[j][rt][ct] = __builtin_amdgcn_mfma_f32_16x16x32_bf16(ah[rt].v8, bl.v8, acc[j][rt][ct], 0, 0, 0);
          acc[j][rt][ct] = __builtin_amdgcn_mfma_f32_16x16x32_bf16(al[rt].v8, bh.v8, acc[j][rt][ct], 0, 0, 0);
        }
      }
    }

    if (cs == 15) {
      // epilogue: scale + store + running row-argmax (k ascending => strict > keeps smallest k)
#pragma unroll
      for (int j = 0; j < 2; ++j) {
#pragma unroll
        for (int rt = 0; rt < 4; ++rt) {
#pragma unroll
          for (int reg = 0; reg < 4; ++reg) {
            const int prow = pbase + wr * 64 + rt * 16 + 4 * lg + reg;
            float* dst = out_logit + (size_t)prow * KK + (kcp * 2 + j) * 256 + wc * 64 + l15;
#pragma unroll
            for (int ct = 0; ct < 4; ++ct) {
              const float v = acc[j][rt][ct][reg] * INV_SCALE;
              dst[ct * 16] = v;
              if (v > bestv[rt][reg]) {
                bestv[rt][reg] = v;
                bestk[rt][reg] = (kcp * 2 + j) * 256 + wc * 64 + ct * 16 + l15;
              }
            }
          }
        }
      }
    }
    BARRIER();                    // all waves done with buf `cur` before refill
    if (st + 2 < 32) STAGE(cur, st + 2);
  }

  // reduce each row-best across the 16 l15 lanes (same lg => same row set)
#pragma unroll
  for (int rt = 0; rt < 4; ++rt)
#pragma unroll
    for (int reg = 0; reg < 4; ++reg) {
      float v = bestv[rt][reg]; int k = bestk[rt][reg];
#pragma unroll
      for (int off = 1; off < 16; off <<= 1) {
        const float ov = __shfl_xor(v, off);
        const int   ok = __shfl_xor(k, off);
        if (ov > v || (ov == v && ok < k)) { v = ov; k = ok; }
      }
      bestv[rt][reg] = v; bestk[rt][reg] = k;
    }
  if (t < 128) candCnt[t] = 0;
  if (wc == 0 && l15 == 0) {
#pragma unroll
    for (int rt = 0; rt < 4; ++rt)
#pragma unroll
      for (int reg = 0; reg < 4; ++reg) {
        const int r = wr * 64 + rt * 16 + 4 * lg + reg;
        rowBv[r] = bestv[rt][reg]; rowBk[r] = bestk[rt][reg];
      }
  }
  __syncthreads();
#pragma unroll
  for (int m = 1; m < 4; ++m) {
    if (wc == m && l15 == 0) {
#pragma unroll
      for (int rt = 0; rt < 4; ++rt)
#pragma unroll
        for (int reg = 0; reg < 4; ++reg) {
          const int r = wr * 64 + rt * 16 + 4 * lg + reg;
          const float v = bestv[rt][reg]; const int k = bestk[rt][reg];
          if (v > rowBv[r] || (v == rowBv[r] && k < rowBk[r])) { rowBv[r] = v; rowBk[r] = k; }
        }
    }
    __syncthreads();
  }

  // candidate scan: all k within MARGIN of the row's f32 max (L2-hot re-read)
  {
    const int r = t >> 2, qd = t & 3;
    const size_t base = (size_t)(pbase + r) * KK + qd * 256;
    const float thr = rowBv[r] - MARGIN;
    for (int x = 0; x < 64; ++x) {
      const float4 f = *(const float4*)&out_logit[base + x * 4];
      const int kb = qd * 256 + x * 4;
      if (f.x >= thr) { int id = atomicAdd(&candCnt[r], 1); if (id < 8) candK[r][id] = kb + 0; }
      if (f.y >= thr) { int id = atomicAdd(&candCnt[r], 1); if (id < 8) candK[r][id] = kb + 1; }
      if (f.z >= thr) { int id = atomicAdd(&candCnt[r], 1); if (id < 8) candK[r][id] = kb + 2; }
      if (f.w >= thr) { int id = atomicAdd(&candCnt[r], 1); if (id < 8) candK[r][id] = kb + 3; }
    }
  }
  __syncthreads();

  // finalize: cnt==1 -> f32 argmax exact enough; cnt>=2 -> f64 rescore (rare)
  const int wv = t >> 6, lane_ = t & 63;
  for (int rr = 0; rr < 16; ++rr) {
    const int r = wv * 16 + rr;
    const int p = pbase + r;
    int cnt = candCnt[r]; if (cnt > 8) cnt = 8;
    if (cnt <= 1) {
      if (lane_ == 0) {
        const int tc0 = rowBk[r];
        trueCode[p] = tc0;
        atomicAdd(&binCnt[n * KK + tc0], 1);
      }
    } else {
      const float* Ap = latent + (size_t)(p >> 12) * 2097152 + (p & 4095);
      int ks[8];
#pragma unroll
      for (int m = 0; m < 8; ++m) ks[m] = candK[r][m < cnt ? m : 0];
      double part[8] = {0, 0, 0, 0, 0, 0, 0, 0};
#pragma unroll
      for (int jj = 0; jj < 8; ++jj) {
        const int c = jj * 64 + lane_;
        const double lv = (double)Ap[(size_t)c * 4096];
#pragma unroll
        for (int m = 0; m < 8; ++m)
          if (m < cnt) part[m] += lv * WT64[(size_t)ks[m] * CIN + c];
      }
#pragma unroll
      for (int m = 0; m < 8; ++m)
        for (int off = 32; off; off >>= 1) part[m] += __shfl_xor(part[m], off);
      if (lane_ == 0) {
        double bv = -1.0e300; int bkk = KK;
#pragma unroll
        for (int m = 0; m < 8; ++m)
          if (m < cnt && (part[m] > bv || (part[m] == bv && ks[m] < bkk))) { bv = part[m]; bkk = ks[m]; }
        trueCode[p] = bkk;
        atomicAdd(&binCnt[n * KK + bkk], 1);
      }
    }
  }
}

// ---------------- per-row sampling: wave-per-row, no block syncs ----------------
__global__ __launch_bounds__(256) void k_final(const float* __restrict__ logit,
                                               const int* __restrict__ trueCode,
                                               const int* __restrict__ binCnt,
                                               float* __restrict__ out_code,
                                               float* __restrict__ out_tc,
                                               float* __restrict__ out_freq,
                                               int* __restrict__ code_int,
                                               uint32_t r1a, uint32_t r1b,
                                               uint32_t r2a, uint32_t r2b,
                                               uint32_t r3a, uint32_t r3b) {
  const int lane = threadIdx.x & 63;
  const int p = blockIdx.x * 4 + (threadIdx.x >> 6);
  const float* Lr = logit + (size_t)p * KK + lane * 16;

  float l[16];
#pragma unroll
  for (int i = 0; i < 4; ++i) {
    const float4 f = *(const float4*)(Lr + i * 4);
    l[i*4+0] = f.x; l[i*4+1] = f.y; l[i*4+2] = f.z; l[i*4+3] = f.w;
  }

  float m = l[0];
#pragma unroll
  for (int i = 1; i < 16; ++i) m = fmaxf(m, l[i]);
  for (int off = 32; off; off >>= 1) m = fmaxf(m, __shfl_xor(m, off));

  float e[16], s = 0.f;
#pragma unroll
  for (int i = 0; i < 16; ++i) { e[i] = __expf(l[i] - m); s += e[i]; }
  for (int off = 32; off; off >>= 1) s += __shfl_xor(s, off);

  const int tc = trueCode[p];
  const float fq = (float)binCnt[(p >> 12) * KK + tc];
  uint32_t d0, d1; tf2x32(r2a, r2b, 0u, (uint32_t)p, d0, d1);
  const bool drop = bits_to_u(d0 ^ d1) < fq * (1.0f / 4096.0f);

  const float thr = s * 0.0009765625f;
  float bv = -3.0e38f; int bk = 0;
#pragma unroll
  for (int j = 0; j < 16; ++j) {
    const int k = lane * 16 + j;
    const uint32_t idx = (uint32_t)(p * KK + k);
    uint32_t m0, m1, g0, g1;
    tf2x32(r1a, r1b, 0u, idx, m0, m1);
    tf2x32(r3a, r3b, 0u, idx, g0, g1);
    const bool mk = ((e[j] >= thr) && (bits_to_u(m0 ^ m1) * s < e[j])) || (k == tc && drop);
    const float u3  = fmaxf(bits_to_u(g0 ^ g1), 1.17549435082228751e-38f);
    const float gum = -__logf(-logf(u3));
    const float z = mk ? (gum - 1.0e9f) : (l[j] + gum);
    if (z > bv) { bv = z; bk = k; }
  }
  for (int off = 32; off; off >>= 1) {
    const float ov = __shfl_xor(bv, off);
    const int   ok = __shfl_xor(bk, off);
    if (ov > bv || (ov == bv && ok < bk)) { bv = ov; bk = ok; }
  }
  if (lane == 0) {
    out_code[p] = (float)bk; code_int[p] = bk;
    out_tc[p] = (float)tc;   out_freq[p] = fq;
  }
}

// ---------------- quantized[n][o][h][w] = v[code[n,h,w]][o] ----------------
__global__ __launch_bounds__(256) void k_quant(const float* __restrict__ v,
                                               const int* __restrict__ code_int,
                                               float* __restrict__ outq) {
  const int rb = blockIdx.x;
  const int n = rb >> 6, h = rb & 63;
  const int t = threadIdx.x;
  __shared__ int codes[64];
  if (t < 64) codes[t] = code_int[rb * 64 + t];
  __syncthreads();
  const int w = t & 63, og = t >> 6;
  const float* vr = v + (size_t)codes[w] * COUT;
  float* ob = outq + (size_t)n * COUT * 4096 + (size_t)h * 64 + w;
  for (int o = og * 128; o < og * 128 + 128; ++o)
    ob[(size_t)o * 4096] = vr[o];
}

__global__ __launch_bounds__(256) void k_bincopy(const int* __restrict__ binCnt,
                                                 float* __restrict__ outb) {
  const int i = blockIdx.x * 256 + threadIdx.x;
  if (i < NB * KK) outb[i] = (float)binCnt[i];
}

// ---------------- host launch ----------------
extern "C" void kernel_launch(void* const* d_in, const int* in_sizes, int n_in,
                              void* d_out, int out_size, void* d_ws, size_t ws_size,
                              hipStream_t stream) {
  const float* latent   = (const float*)d_in[0];
  const float* codebook = (const float*)d_in[1];
  const float* wq       = (const float*)d_in[2];
  const float* wk       = (const float*)d_in[3];
  const float* wv       = (const float*)d_in[4];

  float* out = (float*)d_out;
  float* out_quant = out;
  float* out_code  = out + 33554432;
  float* out_logit = out + 33619968;
  float* out_tc    = out + 100728832;
  float* out_freq  = out + 100794368;
  float* out_bin   = out + 100859904;

  double*   WT64 = (double*)  out_quant;                 // 4 MiB (overwritten by k_quant)
  uint16_t* Wph  = (uint16_t*)(out_quant + 1048576);     // 1 MiB
  uint16_t* Wpl  = (uint16_t*)(out_quant + 1310720);     // 1 MiB

  char* ws = (char*)d_ws;
  uint16_t* Apk     = (uint16_t*)(ws);                   // 128 MiB [cs][p][8 quads]
  double*   kmatT64 = (double*)(ws);                     // aliases Apk head (dead before k_aprep)
  float*    v       = (float*)(ws + 134217728);
  int*      trueCode= (int*)  (ws + 136314880);
  int*      code_int= (int*)  (ws + 136577024);
  int*      binCnt  = (int*)  (ws + 136839168);

  uint32_t r1a, r1b, r2a, r2b, r3a, r3b;
  tf2x32(0u, 1234u, 0u, 0u, r1a, r1b);
  tf2x32(0u, 1234u, 0u, 1u, r2a, r2b);
  tf2x32(0u, 1234u, 0u, 2u, r3a, r3b);

  hipMemsetAsync(binCnt, 0, NB * KK * sizeof(int), stream);
  k_prep  <<<128,   256, 0, stream>>>(codebook, wk, wv, kmatT64, v);
  k_wfold <<<64,    256, 0, stream>>>(wq, kmatT64, WT64, Wph, Wpl);
  k_aprep <<<1024,  256, 0, stream>>>(latent, Apk);
  k_logit <<<512,   512, 0, stream>>>(Apk, Wph, Wpl, latent, WT64,
                                      out_logit, trueCode, binCnt);
  k_final <<<16384, 256, 0, stream>>>(out_logit, trueCode, binCnt,
                                      out_code, out_tc, out_freq, code_int,
                                      r1a, r1b, r2a, r2b, r3a, r3b);
  k_quant <<<1024,  256, 0, stream>>>(v, code_int, out_quant);
  k_bincopy<<<64,   256, 0, stream>>>(binCnt, out_bin);
}

// Round 10
// 909.247 us; speedup vs baseline: 1.0993x; 1.0993x over previous
//
#include <hip/hip_runtime.h>
#include <stdint.h>
#include <stddef.h>

#define NB   16
#define CIN  512
#define COUT 512
#define KK   1024

#define MARGIN    2e-5f
#define INV_SCALE 0.04419417382415922f   // 1/sqrt(512)

typedef short short4v __attribute__((ext_vector_type(4)));
typedef short short8v __attribute__((ext_vector_type(8)));
typedef float f32x4  __attribute__((ext_vector_type(4)));

union Frag { short4v h[2]; short8v v8; };

// ---------------- threefry2x32 (JAX-compatible, 20 rounds) ----------------
__host__ __device__ inline void tf2x32(uint32_t k0, uint32_t k1,
                                       uint32_t x0, uint32_t x1,
                                       uint32_t& o0, uint32_t& o1) {
  uint32_t ks2 = k0 ^ k1 ^ 0x1BD11BDAu;
  x0 += k0; x1 += k1;
#define TF_RND(r) { x0 += x1; x1 = (x1 << r) | (x1 >> (32 - r)); x1 ^= x0; }
  TF_RND(13) TF_RND(15) TF_RND(26) TF_RND(6)
  x0 += k1;  x1 += ks2 + 1u;
  TF_RND(17) TF_RND(29) TF_RND(16) TF_RND(24)
  x0 += ks2; x1 += k0 + 2u;
  TF_RND(13) TF_RND(15) TF_RND(26) TF_RND(6)
  x0 += k0;  x1 += k1 + 3u;
  TF_RND(17) TF_RND(29) TF_RND(16) TF_RND(24)
  x0 += k1;  x1 += ks2 + 4u;
  TF_RND(13) TF_RND(15) TF_RND(26) TF_RND(6)
  x0 += ks2; x1 += k0 + 5u;
#undef TF_RND
  o0 = x0; o1 = x1;
}

__device__ inline float bits_to_u(uint32_t b) {
  return __uint_as_float((b >> 9) | 0x3f800000u) - 1.0f;
}

__device__ __host__ inline uint16_t f2bf(float f) {
  union { float f; uint32_t u; } c; c.f = f;
  uint32_t r = (c.u + 0x7fffu + ((c.u >> 16) & 1u)) >> 16;
  return (uint16_t)r;
}
__device__ inline float bf2f(uint16_t h) {
  union { uint32_t u; float f; } c; c.u = ((uint32_t)h) << 16;
  return c.f;
}

// permuted column position inside a 32-c slice: group g holds {4g..4g+3, 4g+16..4g+19}
__device__ inline int permpos(int c) {
  const int base32 = c & ~31, within = c & 31;
  const int g = (within >> 2) & 3;
  const int e = (within & 16) ? (4 + (within & 3)) : (within & 3);
  return base32 + g * 8 + e;
}

// ---------------- fused: k_prep (blocks 0..127) + k_aprep (blocks 128..1151) ----------------
__global__ __launch_bounds__(256) void k_combo(const float* __restrict__ cb,
                                               const float* __restrict__ wk,
                                               const float* __restrict__ wv,
                                               const float* __restrict__ latent,
                                               double* __restrict__ kmatT64,
                                               float* __restrict__ v,
                                               uint16_t* __restrict__ Apk) {
  __shared__ __align__(16) char sm[34816];
  const int t = threadIdx.x;
  if (blockIdx.x < 128) {
    // ---- prep: kmatT64[o][k] (f64), v[k][o] ----
    float (*rows)[CIN] = (float(*)[CIN])sm;    // 8x512 f32 = 16 KB
    const int k0 = blockIdx.x * 8;
#pragma unroll
    for (int kk = 0; kk < 8; ++kk)
      for (int c = t; c < CIN; c += 256) rows[kk][c] = cb[(size_t)(k0 + kk) * CIN + c];
    __syncthreads();
#pragma unroll
    for (int oo = 0; oo < 2; ++oo) {
      const int o = t + oo * 256;
      const float* kr = wk + (size_t)o * CIN;
      const float* vr = wv + (size_t)o * CIN;
      double ak[8] = {0,0,0,0,0,0,0,0}, av[8] = {0,0,0,0,0,0,0,0};
      for (int c = 0; c < CIN; c += 4) {
        const float4 k4 = *(const float4*)(kr + c);
        const float4 v4 = *(const float4*)(vr + c);
#pragma unroll
        for (int kk = 0; kk < 8; ++kk) {
          const float4 c4 = *(const float4*)&rows[kk][c];
          ak[kk] += (double)c4.x * (double)k4.x + (double)c4.y * (double)k4.y
                  + (double)c4.z * (double)k4.z + (double)c4.w * (double)k4.w;
          av[kk] += (double)c4.x * (double)v4.x + (double)c4.y * (double)v4.y
                  + (double)c4.z * (double)v4.z + (double)c4.w * (double)v4.w;
        }
      }
#pragma unroll
      for (int kk = 0; kk < 8; ++kk) {
        kmatT64[(size_t)o * KK + k0 + kk] = ak[kk];
        v[(size_t)(k0 + kk) * COUT + o]  = (float)av[kk];
      }
    }
  } else {
    // ---- aprep: latent NCHW f32 -> Apk[cs][p][8 quads of [hi4|lo4]] ----
    float (*T)[68] = (float(*)[68])sm;         // 128x68 f32 = 34 KB
    const int rb = blockIdx.x - 128, n = rb >> 6, h = rb & 63;
    for (int c0 = 0; c0 < 512; c0 += 128) {
      const int c2 = t >> 1, wh = (t & 1) * 32;
      const float* src = latent + (size_t)n * 2097152 + (size_t)(c0 + c2) * 4096 + h * 64 + wh;
#pragma unroll
      for (int i = 0; i < 8; ++i)
        *(float4*)&T[c2][wh + i*4] = *(const float4*)(src + i*4);
      __syncthreads();
      const int w = t & 63, cp = t >> 6;
      const int cs = (c0 >> 5) + cp;          // 0..15
      const int p = rb * 64 + w;
      uint16_t* dst = Apk + ((size_t)cs * 65536 + p) * 64;
#pragma unroll
      for (int q = 0; q < 8; ++q) {
        short8v vv;
#pragma unroll
        for (int j = 0; j < 4; ++j) {
          const float f = T[cp*32 + (q & 3) * 4 + (q >> 2) * 16 + j][w];
          const uint16_t hb = f2bf(f);
          vv[j]     = (short)hb;
          vv[4 + j] = (short)f2bf(f - bf2f(hb));
        }
        *(short8v*)(dst + q * 8) = vv;
      }
      __syncthreads();
    }
  }
}

// ---- W[c][k]=sum_o wq[o][c]*kmat[k][o]; emit WT64[k][c] f64 + frag-major bf16 hi/lo ----
__global__ __launch_bounds__(256) void k_wfold(const float* __restrict__ wq,
                                               const double* __restrict__ kmatT64,
                                               double* __restrict__ WT64,
                                               uint16_t* __restrict__ Wph,
                                               uint16_t* __restrict__ Wpl) {
  __shared__ __align__(16) float  As[16][64];    // [o][c]
  __shared__ __align__(16) double Bs[16][128];   // [o][k]
  const int t  = threadIdx.x;
  const int cb = (blockIdx.x >> 3) * 64;
  const int kb = (blockIdx.x & 7) * 128;
  const int tc = t >> 4, tk = t & 15;

  double acc[4][8];
#pragma unroll
  for (int i = 0; i < 4; ++i)
#pragma unroll
    for (int j = 0; j < 8; ++j) acc[i][j] = 0.0;

  for (int o0 = 0; o0 < COUT; o0 += 16) {
    {
      const int o2 = t >> 4, c4 = (t & 15) * 4;
      float4 f = *(const float4*)&wq[(size_t)(o0 + o2) * CIN + cb + c4];
      As[o2][c4+0] = f.x; As[o2][c4+1] = f.y; As[o2][c4+2] = f.z; As[o2][c4+3] = f.w;
    }
    {
      const int o2 = t >> 4, k8 = (t & 15) * 8;
      const double* src = &kmatT64[(size_t)(o0 + o2) * KK + kb + k8];
#pragma unroll
      for (int j = 0; j < 8; ++j) Bs[o2][k8 + j] = src[j];
    }
    __syncthreads();
#pragma unroll 4
    for (int o2 = 0; o2 < 16; ++o2) {
      double a[4], b[8];
#pragma unroll
      for (int i = 0; i < 4; ++i) a[i] = (double)As[o2][tc*4 + i];
#pragma unroll
      for (int j = 0; j < 8; ++j) b[j] = Bs[o2][tk*8 + j];
#pragma unroll
      for (int i = 0; i < 4; ++i)
#pragma unroll
        for (int j = 0; j < 8; ++j) acc[i][j] += a[i] * b[j];
    }
    __syncthreads();
  }
#pragma unroll
  for (int i = 0; i < 4; ++i) {
    const int c = cb + tc*4 + i;
    const int pp = permpos(c);
#pragma unroll
    for (int j = 0; j < 8; ++j) {
      const int k = kb + tk*8 + j;
      const double a = acc[i][j];
      WT64[(size_t)k * CIN + c] = a;
      const float wf = (float)a;
      const uint16_t hb = f2bf(wf);
      const float lof = wf - bf2f(hb);
      Wph[(size_t)k * CIN + pp] = hb;
      Wpl[(size_t)k * CIN + pp] = f2bf(lof);
    }
  }
}

// ---- stage B slice (32 KB) via global_load_lds, pre-swizzled source (256 thr) ----
#define STAGE_B(buf_, st_) do {                                            \
  const int kc_ = (st_) >> 4, cs_ = (st_) & 15;                            \
  _Pragma("unroll")                                                        \
  for (int i_ = 0; i_ < 8; ++i_) {                                         \
    const int half_ = i_ >> 2;                                             \
    const int D_ = (i_ & 3) * 4096 + wave * 1024 + lane * 16;              \
    const int kcol_ = D_ >> 6;                                             \
    const int bs_ = ((D_ >> 4) & 3) ^ ((kcol_ >> 1) & 3);                  \
    const uint16_t* gsrc_ = (half_ ? Wpl : Wph) +                          \
        ((size_t)(kc_ * 256 + kcol_) * 512 + cs_ * 32 + bs_ * 8);          \
    uint16_t* ldst_ = &Bst[buf_][half_ * 8192 + (D_ >> 1)];                \
    __builtin_amdgcn_global_load_lds(                                      \
        (const __attribute__((address_space(1))) uint32_t*)gsrc_,          \
        (__attribute__((address_space(3))) uint32_t*)ldst_, 16, 0, 0);     \
  } } while (0)

// ---- stage A slice (8 KB: 64 rows x 32 c packed hi|lo), quad-XOR pre-swizzled ----
#define STAGE_A(buf_, st_) do {                                            \
  const int cs_ = (st_) & 15;                                              \
  _Pragma("unroll")                                                        \
  for (int i_ = 0; i_ < 2; ++i_) {                                         \
    const int D_ = i_ * 4096 + t * 16;                                     \
    const int row_ = D_ >> 7;                                              \
    const int q_ = ((D_ >> 4) & 7) ^ (row_ & 7);                           \
    const uint16_t* gsrc_ = Apk +                                          \
        ((size_t)cs_ * 65536 + pbase + row_) * 64 + q_ * 8;                \
    uint16_t* ldst_ = &Ast[buf_][D_ >> 1];                                 \
    __builtin_amdgcn_global_load_lds(                                      \
        (const __attribute__((address_space(1))) uint32_t*)gsrc_,          \
        (__attribute__((address_space(3))) uint32_t*)ldst_, 16, 0, 0);     \
  } } while (0)

// ---------------- logit GEMM: R7-bench structure + in-register top-2 argmax ----------------
__global__ __launch_bounds__(256, 2) void k_logit(
    const uint16_t* __restrict__ Apk,
    const uint16_t* __restrict__ Wph, const uint16_t* __restrict__ Wpl,
    const float* __restrict__ latent, const double* __restrict__ WT64,
    float* __restrict__ out_logit, int* __restrict__ trueCode, int* __restrict__ binCnt) {
  __shared__ __align__(16) char smem[81920];
  uint16_t (*Bst)[16384] = (uint16_t(*)[16384])smem;            // 2 x 32 KB
  uint16_t (*Ast)[4096]  = (uint16_t(*)[4096])(smem + 65536);   // 2 x 8 KB
  // post-loop scratch overlays Ast[0] (only touched after the final barrier):
  float* rv1     = (float*)(smem + 65536);                      // 64 f32
  int*   rk1     = (int*)  (smem + 65536 + 256);
  float* rv2     = (float*)(smem + 65536 + 512);
  int*   rk2     = (int*)  (smem + 65536 + 768);
  int*   candCnt = (int*)  (smem + 65536 + 1024);               // 64 i32
  int  (*candK)[8] = (int(*)[8])(smem + 65536 + 1280);          // 64x8 i32

  const int t = threadIdx.x;
  const int wave = t >> 6, lane = t & 63;
  const int wr = wave >> 1, wc = wave & 1;
  const int rb = blockIdx.x, n = rb >> 6;
  const int pbase = rb * 64;
  const int lg = lane >> 4, l15 = lane & 15;

  float v1_[2][4], v2_[2][4]; int k1_[2][4], k2_[2][4];
#pragma unroll
  for (int rt = 0; rt < 2; ++rt)
#pragma unroll
    for (int reg = 0; reg < 4; ++reg) {
      v1_[rt][reg] = -3.0e38f; k1_[rt][reg] = 0x7fffffff;
      v2_[rt][reg] = -3.0e38f; k2_[rt][reg] = 0x7fffffff;
    }

  f32x4 acc[2][8];

  STAGE_A(0, 0);
  STAGE_B(0, 0);
  __syncthreads();

  for (int st = 0; st < 64; ++st) {
    const int cur = st & 1, kc = st >> 4, cs = st & 15;
    if (cs == 0) {
#pragma unroll
      for (int rt = 0; rt < 2; ++rt)
#pragma unroll
        for (int ct = 0; ct < 8; ++ct) acc[rt][ct] = (f32x4){0.f, 0.f, 0.f, 0.f};
    }
    if (st < 63) { STAGE_A(cur ^ 1, st + 1); STAGE_B(cur ^ 1, st + 1); }

    Frag ah[2], al[2];
#pragma unroll
    for (int rt = 0; rt < 2; ++rt) {
      const int row = wr * 32 + rt * 16 + l15;
      const uint16_t* ab = &Ast[cur][row * 64];
      const int s0 = (lg ^ (row & 7)) * 8;
      Frag f0, f1;
      f0.v8 = *(const short8v*)(ab + s0);
      f1.v8 = *(const short8v*)(ab + (s0 ^ 32));
      ah[rt].h[0] = f0.h[0]; ah[rt].h[1] = f1.h[0];
      al[rt].h[0] = f0.h[1]; al[rt].h[1] = f1.h[1];
    }

#pragma unroll
    for (int ct = 0; ct < 8; ++ct) {
      const int kcol = wc * 128 + ct * 16 + l15;
      const int sw = lg ^ ((kcol >> 1) & 3);
      Frag bh, bl;
      bh.v8 = *(const short8v*)&Bst[cur][kcol * 32 + sw * 8];
      bl.v8 = *(const short8v*)&Bst[cur][8192 + kcol * 32 + sw * 8];
#pragma unroll
      for (int rt = 0; rt < 2; ++rt) {
        acc[rt][ct] = __builtin_amdgcn_mfma_f32_16x16x32_bf16(ah[rt].v8, bh.v8, acc[rt][ct], 0, 0, 0);
        acc[rt][ct] = __builtin_amdgcn_mfma_f32_16x16x32_bf16(ah[rt].v8, bl.v8, acc[rt][ct], 0, 0, 0);
        acc[rt][ct] = __builtin_amdgcn_mfma_f32_16x16x32_bf16(al[rt].v8, bh.v8, acc[rt][ct], 0, 0, 0);
      }
    }
    if (cs == 15) {
      // epilogue: scale + store + running per-row TOP-2 (value, k)
#pragma unroll
      for (int rt = 0; rt < 2; ++rt) {
#pragma unroll
        for (int reg = 0; reg < 4; ++reg) {
          const int prow = pbase + wr * 32 + rt * 16 + 4 * lg + reg;
          float* dst = out_logit + (size_t)prow * KK + kc * 256 + wc * 128 + l15;
          float v1 = v1_[rt][reg], v2 = v2_[rt][reg];
          int   k1 = k1_[rt][reg], k2 = k2_[rt][reg];
#pragma unroll
          for (int ct = 0; ct < 8; ++ct) {
            const float vv = acc[rt][ct][reg] * INV_SCALE;
            dst[ct * 16] = vv;
            const int kk = kc * 256 + wc * 128 + ct * 16 + l15;
            if (vv > v1 || (vv == v1 && kk < k1)) { v2 = v1; k2 = k1; v1 = vv; k1 = kk; }
            else if (vv > v2 || (vv == v2 && kk < k2)) { v2 = vv; k2 = kk; }
          }
          v1_[rt][reg] = v1; v2_[rt][reg] = v2;
          k1_[rt][reg] = k1; k2_[rt][reg] = k2;
        }
      }
    }
    __syncthreads();
  }

  // 16-lane shuffle top-2 merge (l15 group shares a row for fixed lg)
#pragma unroll
  for (int rt = 0; rt < 2; ++rt)
#pragma unroll
    for (int reg = 0; reg < 4; ++reg) {
      float v1 = v1_[rt][reg], v2 = v2_[rt][reg];
      int   k1 = k1_[rt][reg], k2 = k2_[rt][reg];
#pragma unroll
      for (int off = 1; off < 16; off <<= 1) {
        const float o1 = __shfl_xor(v1, off); const int ok1 = __shfl_xor(k1, off);
        const float o2 = __shfl_xor(v2, off); const int ok2 = __shfl_xor(k2, off);
        const bool aw = (v1 > o1) || (v1 == o1 && k1 < ok1);
        float n1, n2; int nk1, nk2;
        if (aw) {
          n1 = v1; nk1 = k1;
          if ((o1 > v2) || (o1 == v2 && ok1 < k2)) { n2 = o1; nk2 = ok1; }
          else { n2 = v2; nk2 = k2; }
        } else {
          n1 = o1; nk1 = ok1;
          if ((v1 > o2) || (v1 == o2 && k1 < ok2)) { n2 = v1; nk2 = k1; }
          else { n2 = o2; nk2 = ok2; }
        }
        v1 = n1; k1 = nk1; v2 = n2; k2 = nk2;
      }
      v1_[rt][reg] = v1; v2_[rt][reg] = v2;
      k1_[rt][reg] = k1; k2_[rt][reg] = k2;
    }
  if (wc == 0 && l15 == 0) {
#pragma unroll
    for (int rt = 0; rt < 2; ++rt)
#pragma unroll
      for (int reg = 0; reg < 4; ++reg) {
        const int r = wr * 32 + rt * 16 + 4 * lg + reg;
        rv1[r] = v1_[rt][reg]; rk1[r] = k1_[rt][reg];
        rv2[r] = v2_[rt][reg]; rk2[r] = k2_[rt][reg];
      }
  }
  __syncthreads();
  if (wc == 1 && l15 == 0) {
#pragma unroll
    for (int rt = 0; rt < 2; ++rt)
#pragma unroll
      for (int reg = 0; reg < 4; ++reg) {
        const int r = wr * 32 + rt * 16 + 4 * lg + reg;
        const float a1 = rv1[r], a2 = rv2[r];
        const int   ak1 = rk1[r], ak2 = rk2[r];
        const float b1 = v1_[rt][reg], b2 = v2_[rt][reg];
        const int   bk1 = k1_[rt][reg], bk2 = k2_[rt][reg];
        const bool aw = (a1 > b1) || (a1 == b1 && ak1 < bk1);
        float n1, n2; int nk1, nk2;
        if (aw) {
          n1 = a1; nk1 = ak1;
          if ((b1 > a2) || (b1 == a2 && bk1 < ak2)) { n2 = b1; nk2 = bk1; }
          else { n2 = a2; nk2 = ak2; }
        } else {
          n1 = b1; nk1 = bk1;
          if ((a1 > b2) || (a1 == b2 && ak1 < bk2)) { n2 = a1; nk2 = ak1; }
          else { n2 = b2; nk2 = bk2; }
        }
        rv1[r] = n1; rk1[r] = nk1; rv2[r] = n2; rk2[r] = nk2;
      }
  }
  __syncthreads();

  // finalize: wide gap -> direct trueCode; narrow -> wave-local scan + f64 rescore (rare)
  const int wv = t >> 6, lane_ = t & 63;
  for (int rr = 0; rr < 16; ++rr) {
    const int r = wv * 16 + rr;
    const int p = pbase + r;
    const float mv1 = rv1[r], mv2 = rv2[r];
    if (mv1 - mv2 > MARGIN) {
      if (lane_ == 0) {
        const int tc0 = rk1[r];
        trueCode[p] = tc0;
        atomicAdd(&binCnt[n * KK + tc0], 1);
      }
    } else {
      // wave-local candidate scan of this row (L2-hot; rare path)
      if (lane_ == 0) candCnt[r] = 0;
      __builtin_amdgcn_sched_barrier(0);
      asm volatile("s_waitcnt lgkmcnt(0)" ::: "memory");
      __builtin_amdgcn_sched_barrier(0);
      {
        const float thr = mv1 - MARGIN;
        const float* src = out_logit + (size_t)p * KK + lane_ * 16;
#pragma unroll
        for (int i = 0; i < 4; ++i) {
          const float4 f = *(const float4*)(src + i * 4);
          const int kb = lane_ * 16 + i * 4;
          if (f.x >= thr) { int id = atomicAdd(&candCnt[r], 1); if (id < 8) candK[r][id] = kb + 0; }
          if (f.y >= thr) { int id = atomicAdd(&candCnt[r], 1); if (id < 8) candK[r][id] = kb + 1; }
          if (f.z >= thr) { int id = atomicAdd(&candCnt[r], 1); if (id < 8) candK[r][id] = kb + 2; }
          if (f.w >= thr) { int id = atomicAdd(&candCnt[r], 1); if (id < 8) candK[r][id] = kb + 3; }
        }
      }
      __builtin_amdgcn_sched_barrier(0);
      asm volatile("s_waitcnt lgkmcnt(0)" ::: "memory");
      __builtin_amdgcn_sched_barrier(0);
      int cnt = candCnt[r]; if (cnt > 8) cnt = 8;
      const float* Ap = latent + (size_t)(p >> 12) * 2097152 + (p & 4095);
      int ks[8];
#pragma unroll
      for (int m = 0; m < 8; ++m) ks[m] = candK[r][m < cnt ? m : 0];
      double part[8] = {0, 0, 0, 0, 0, 0, 0, 0};
#pragma unroll
      for (int jj = 0; jj < 8; ++jj) {
        const int c = jj * 64 + lane_;
        const double lv = (double)Ap[(size_t)c * 4096];
#pragma unroll
        for (int m = 0; m < 8; ++m)
          if (m < cnt) part[m] += lv * WT64[(size_t)ks[m] * CIN + c];
      }
#pragma unroll
      for (int m = 0; m < 8; ++m)
        for (int off = 32; off; off >>= 1) part[m] += __shfl_xor(part[m], off);
      if (lane_ == 0) {
        double bv = -1.0e300; int bkk = KK;
#pragma unroll
        for (int m = 0; m < 8; ++m)
          if (m < cnt && (part[m] > bv || (part[m] == bv && ks[m] < bkk))) { bv = part[m]; bkk = ks[m]; }
        trueCode[p] = bkk;
        atomicAdd(&binCnt[n * KK + bkk], 1);
      }
    }
  }
}

// ---------------- per-row sampling: wave-per-row, no block syncs ----------------
__global__ __launch_bounds__(256) void k_final(const float* __restrict__ logit,
                                               const int* __restrict__ trueCode,
                                               const int* __restrict__ binCnt,
                                               float* __restrict__ out_code,
                                               float* __restrict__ out_tc,
                                               float* __restrict__ out_freq,
                                               int* __restrict__ code_int,
                                               uint32_t r1a, uint32_t r1b,
                                               uint32_t r2a, uint32_t r2b,
                                               uint32_t r3a, uint32_t r3b) {
  const int lane = threadIdx.x & 63;
  const int p = blockIdx.x * 4 + (threadIdx.x >> 6);
  const float* Lr = logit + (size_t)p * KK + lane * 16;

  float l[16];
#pragma unroll
  for (int i = 0; i < 4; ++i) {
    const float4 f = *(const float4*)(Lr + i * 4);
    l[i*4+0] = f.x; l[i*4+1] = f.y; l[i*4+2] = f.z; l[i*4+3] = f.w;
  }

  float m = l[0];
#pragma unroll
  for (int i = 1; i < 16; ++i) m = fmaxf(m, l[i]);
  for (int off = 32; off; off >>= 1) m = fmaxf(m, __shfl_xor(m, off));

  float e[16], s = 0.f;
#pragma unroll
  for (int i = 0; i < 16; ++i) { e[i] = __expf(l[i] - m); s += e[i]; }
  for (int off = 32; off; off >>= 1) s += __shfl_xor(s, off);

  const int tc = trueCode[p];
  const float fq = (float)binCnt[(p >> 12) * KK + tc];
  uint32_t d0, d1; tf2x32(r2a, r2b, 0u, (uint32_t)p, d0, d1);
  const bool drop = bits_to_u(d0 ^ d1) < fq * (1.0f / 4096.0f);

  const float thr = s * 0.0009765625f;
  float bv = -3.0e38f; int bk = 0;
#pragma unroll
  for (int j = 0; j < 16; ++j) {
    const int k = lane * 16 + j;
    const uint32_t idx = (uint32_t)(p * KK + k);
    uint32_t m0, m1, g0, g1;
    tf2x32(r1a, r1b, 0u, idx, m0, m1);
    tf2x32(r3a, r3b, 0u, idx, g0, g1);
    const bool mk = ((e[j] >= thr) && (bits_to_u(m0 ^ m1) * s < e[j])) || (k == tc && drop);
    const float u3  = fmaxf(bits_to_u(g0 ^ g1), 1.17549435082228751e-38f);
    const float gum = -__logf(-logf(u3));
    const float z = mk ? (gum - 1.0e9f) : (l[j] + gum);
    if (z > bv) { bv = z; bk = k; }
  }
  for (int off = 32; off; off >>= 1) {
    const float ov = __shfl_xor(bv, off);
    const int   ok = __shfl_xor(bk, off);
    if (ov > bv || (ov == bv && ok < bk)) { bv = ov; bk = ok; }
  }
  if (lane == 0) {
    out_code[p] = (float)bk; code_int[p] = bk;
    out_tc[p] = (float)tc;   out_freq[p] = fq;
  }
}

// ---------------- quantized[n][o][h][w] = v[code[n,h,w]][o]  (float4 stores) ----------------
__global__ __launch_bounds__(256) void k_quant(const float* __restrict__ v,
                                               const int* __restrict__ code_int,
                                               float* __restrict__ outq) {
  __shared__ int codes[4096];
  const int n  = blockIdx.x >> 6;         // 16 n
  const int og = blockIdx.x & 63;         // 64 o-groups of 8
  const int t = threadIdx.x;
  const int4* cp = (const int4*)(code_int + (size_t)n * 4096);
#pragma unroll
  for (int i = 0; i < 4; ++i) ((int4*)codes)[t + i * 256] = cp[t + i * 256];
  __syncthreads();
  float* ob = outq + ((size_t)n * 512 + og * 8) * 4096;
  for (int c = 0; c < 4; ++c) {
    const int pos4 = (c * 256 + t) * 4;
    const int c0 = codes[pos4], c1 = codes[pos4 + 1], c2 = codes[pos4 + 2], c3 = codes[pos4 + 3];
    const float* v0 = v + (size_t)c0 * COUT;
    const float* v1 = v + (size_t)c1 * COUT;
    const float* v2 = v + (size_t)c2 * COUT;
    const float* v3 = v + (size_t)c3 * COUT;
#pragma unroll
    for (int oo = 0; oo < 8; ++oo) {
      const int o = og * 8 + oo;
      float4 val = make_float4(v0[o], v1[o], v2[o], v3[o]);
      *(float4*)(ob + (size_t)oo * 4096 + pos4) = val;
    }
  }
}

__global__ __launch_bounds__(256) void k_bincopy(const int* __restrict__ binCnt,
                                                 float* __restrict__ outb) {
  const int i = blockIdx.x * 256 + threadIdx.x;
  if (i < NB * KK) outb[i] = (float)binCnt[i];
}

// ---------------- host launch ----------------
extern "C" void kernel_launch(void* const* d_in, const int* in_sizes, int n_in,
                              void* d_out, int out_size, void* d_ws, size_t ws_size,
                              hipStream_t stream) {
  const float* latent   = (const float*)d_in[0];
  const float* codebook = (const float*)d_in[1];
  const float* wq       = (const float*)d_in[2];
  const float* wk       = (const float*)d_in[3];
  const float* wv       = (const float*)d_in[4];

  float* out = (float*)d_out;
  float* out_quant = out;
  float* out_code  = out + 33554432;
  float* out_logit = out + 33619968;
  float* out_tc    = out + 100728832;
  float* out_freq  = out + 100794368;
  float* out_bin   = out + 100859904;

  // scratch inside out_quant (all dead before k_quant overwrites):
  double*   WT64    = (double*)  out_quant;                  // [0, 4MB)
  uint16_t* Wph     = (uint16_t*)(out_quant + 1048576);      // [4MB, 5MB)
  uint16_t* Wpl     = (uint16_t*)(out_quant + 1310720);      // [5MB, 6MB)
  double*   kmatT64 = (double*)  (out_quant + 1572864);      // [6MB, 10MB)

  char* ws = (char*)d_ws;
  uint16_t* Apk     = (uint16_t*)(ws);                       // 128 MiB [cs][p][8 quads]
  float*    v       = (float*)(ws + 134217728);
  int*      trueCode= (int*)  (ws + 136314880);
  int*      code_int= (int*)  (ws + 136577024);
  int*      binCnt  = (int*)  (ws + 136839168);

  uint32_t r1a, r1b, r2a, r2b, r3a, r3b;
  tf2x32(0u, 1234u, 0u, 0u, r1a, r1b);
  tf2x32(0u, 1234u, 0u, 1u, r2a, r2b);
  tf2x32(0u, 1234u, 0u, 2u, r3a, r3b);

  hipMemsetAsync(binCnt, 0, NB * KK * sizeof(int), stream);
  k_combo <<<1152,  256, 0, stream>>>(codebook, wk, wv, latent, kmatT64, v, Apk);
  k_wfold <<<64,    256, 0, stream>>>(wq, kmatT64, WT64, Wph, Wpl);
  k_logit <<<1024,  256, 0, stream>>>(Apk, Wph, Wpl, latent, WT64,
                                      out_logit, trueCode, binCnt);
  k_final <<<16384, 256, 0, stream>>>(out_logit, trueCode, binCnt,
                                      out_code, out_tc, out_freq, code_int,
                                      r1a, r1b, r2a, r2b, r3a, r3b);
  k_quant <<<1024,  256, 0, stream>>>(v, code_int, out_quant);
  k_bincopy<<<64,   256, 0, stream>>>(binCnt, out_bin);
}